// Round 5
// baseline (4717.965 us; speedup 1.0000x reference)
//
#include <hip/hip_runtime.h>

// SpectralConv2d (FNO) as a chain of truncated-DFT GEMMs. All fp32 vector math.
// B=8, CIN=COUT=64, H=W=256, M1=M2=32.
//
// Round 4: 2-phase double-buffered K-loop for MODE 1/2 (stage next tile via
// global_load_lds BEFORE compute, single barrier per tile -> global latency
// hides under the FMA phase; MPAIR A-path = load-early/ds_write-late). BK 32->16
// so dbuf keeps the same LDS footprint (D/E 32KB = 5 blocks/CU, B 24KB, A-Z 40KB).
// MODE 0 (A-X) unchanged.

#define PI_D 3.14159265358979323846

// ---------------- DFT table init (once per call; double precision) -------------
__global__ void tab_init(float* __restrict__ ws) {
  int t = blockIdx.x * blockDim.x + threadIdx.x;  // 0..65535
  float* TA = ws;                      // [256][64]
  float* TB = ws + 16384;              // [512][128]
  float* TD = ws + 16384 + 65536;      // [128][512]
  float* TE = ws + 16384 + 2 * 65536;  // [64][256]
  const double w0 = 2.0 * PI_D / 256.0;
  // T_A[n][2k+s]: s=0 -> cos(2pi n k/256), s=1 -> -sin
  if (t < 16384) {
    int n = t >> 6, c = t & 63, k = c >> 1, s = c & 1;
    int m = (n * k) & 255;
    double sv, cv; sincos(w0 * m, &sv, &cv);
    TA[t] = (float)(s ? -sv : cv);
  }
  // T_B[2h+ti][2j+s]: forward e^{-i theta}: [c, s; -s, c]
  {
    int r = t >> 7, c = t & 127;
    int h = r >> 1, ti = r & 1, j = c >> 1, s = c & 1;
    int kx = (j < 32) ? j : 192 + j;
    int m = (kx * h) & 255;
    double sv, cv; sincos(w0 * m, &sv, &cv);
    TB[t] = (float)((ti == s) ? cv : (ti ? sv : -sv));
  }
  // T_D[2j+ti][2h+s]: inverse e^{+i theta}
  {
    int r = t >> 9, c = t & 511;
    int j = r >> 1, ti = r & 1, h = c >> 1, s = c & 1;
    int kx = (j < 32) ? j : 192 + j;
    int m = (kx * h) & 255;
    double sv, cv; sincos(w0 * m, &sv, &cv);
    TD[t] = (float)((ti == s) ? cv : (ti ? -sv : sv));
  }
  // T_E[2k+s][w]: c_k/65536 * (cos | -sin); c_0=1 else 2.
  if (t < 16384) {
    int r = t >> 8, w = t & 255, k = r >> 1, s = r & 1;
    int m = (k * w) & 255;
    double sv, cv; sincos(w0 * m, &sv, &cv);
    double amp = (k == 0 ? 1.0 : 2.0) / 65536.0;
    TE[t] = (float)(s ? -amp * sv : amp * cv);
  }
}

// direct global->LDS async copy, 16B per lane. Dest must be wave-base+lane*16.
__device__ __forceinline__ void gl16(const float* g, float* l) {
  __builtin_amdgcn_global_load_lds(
      (const __attribute__((address_space(1))) void*)g,
      (__attribute__((address_space(3))) void*)l, 16, 0, 0);
}

// ---------------- generic tiled GEMM: out[M][N] = in[M][K] * tab[K][N] ---------
// Input addressing: row base = (row/rdiv)*rmul1 + (row%rdiv)*rmul2,
//                   k offset = (k>>1)*sH + (k&1)*sT.
// MODE 0 (KCONTIG): float4 loads along k (requires sH=2,sT=1). LDS padded,
//                   single-buffer two-barrier loop (unchanged).
// MODE 1 (MQUAD):   rmul2==1 -> float4 = 4 consecutive rows at fixed k;
//                   global_load_lds, double-buffered 2-phase pipeline.
// MODE 2 (MPAIR):   rmul2==2, sT==1 -> float4 = 2 rows x (re,im); global loads
//                   issued early into regs, ds_write after compute (T14 split),
//                   double-buffered 2-phase pipeline.
// Bs staging: MODE!=0 via global_load_lds (dest linear in tid).
// Per-thread tile = TM x 8. Threads = (BM/TM)*(BN/8).
// Wave-local 8x8 lane grid keeps LDS compute reads broadcast (<=2-way = free).
template <int BM, int BN, int TM, int MODE, int BK>
__global__ __launch_bounds__((BM / TM) * (BN / 8), MODE == 0 ? 4 : 5) void gemm_t(
    const float* __restrict__ in, const float* __restrict__ tab,
    float* __restrict__ out, int K, int N, int rdiv, int rmul1, int rmul2,
    int sH, int sT, long inStride, long outStride) {
  constexpr int NT = (BM / TM) * (BN / 8);
  constexpr int CW = BN / 64;  // waves per column band
  constexpr int PAD = (MODE == 0) ? 4 : 0;
  constexpr int NBUF = (MODE == 0) ? 1 : 2;
  __shared__ float As[NBUF][BK][BM + PAD];
  __shared__ float Bs[NBUF][BK][BN + PAD];
  const int tid = threadIdx.x;
  const int wave = tid >> 6, lane = tid & 63;
  const int tx = (wave % CW) * 8 + (lane & 7);
  const int ty = (wave / CW) * 8 + (lane >> 3);
  const long bm = (long)blockIdx.x * BM;
  const int bn = blockIdx.y * BN;
  in += (long)blockIdx.z * inStride;
  out += (long)blockIdx.z * outStride;
  float acc[TM][8] = {};

  long abase = 0;
  int am = 0;
  if constexpr (MODE == 0) {
    am = tid >> 3;
  } else if constexpr (MODE == 1) {
    am = 4 * (tid % (BM / 4));
    int row = (int)bm + am;
    abase = (long)(row / rdiv) * rmul1 + (long)(row % rdiv) * rmul2;
  } else {
    am = 2 * (tid % (BM / 2));
    int row = (int)bm + am;
    abase = (long)(row / rdiv) * rmul1 + (long)(row % rdiv) * rmul2;
  }

  // MPAIR constants
  constexpr int KH = (MODE == 2) ? (NT / (BM / 2)) : 1;       // khi rows/pass
  constexpr int P2 = (MODE == 2) ? ((BK / 2) / KH) : 1;        // passes
  float4 areg[P2];

  // ---- staging helpers ----
  auto stageB = [&](int kt, int ib) {
    int n4 = (tid % (BN / 4)) * 4;
    #pragma unroll
    for (int k = tid / (BN / 4); k < BK; k += (NT / (BN / 4))) {
      gl16(tab + (long)(kt + k) * N + bn + n4, &Bs[ib][k][n4]);
    }
  };
  auto stageA1 = [&](int kt, int ib) {  // MODE 1: gl16 direct
    constexpr int KSTEP = NT / (BM / 4);
    #pragma unroll
    for (int k = tid / (BM / 4); k < BK; k += KSTEP) {
      int kg = kt + k;
      gl16(in + abase + (long)(kg >> 1) * sH + (long)(kg & 1) * sT,
           &As[ib][k][am]);
    }
  };
  auto loadA2 = [&](int kt) {  // MODE 2: global -> regs (issued early)
    #pragma unroll
    for (int i = 0; i < P2; ++i) {
      int khi = tid / (BM / 2) + i * KH;
      areg[i] = *reinterpret_cast<const float4*>(
          in + abase + (long)(kt / 2 + khi) * sH);
    }
  };
  auto writeA2 = [&](int ib) {  // MODE 2: regs -> LDS (late)
    #pragma unroll
    for (int i = 0; i < P2; ++i) {
      int khi = tid / (BM / 2) + i * KH;
      *reinterpret_cast<float2*>(&As[ib][2 * khi][am]) =
          make_float2(areg[i].x, areg[i].z);
      *reinterpret_cast<float2*>(&As[ib][2 * khi + 1][am]) =
          make_float2(areg[i].y, areg[i].w);
    }
  };
  auto compute = [&](int ib) {
    #pragma unroll
    for (int k = 0; k < BK; ++k) {
      float a[TM], b[8];
      const float4* ap = reinterpret_cast<const float4*>(&As[ib][k][ty * TM]);
      #pragma unroll
      for (int i = 0; i < TM / 4; ++i) {
        float4 v = ap[i];
        a[i * 4 + 0] = v.x; a[i * 4 + 1] = v.y;
        a[i * 4 + 2] = v.z; a[i * 4 + 3] = v.w;
      }
      const float4* bp = reinterpret_cast<const float4*>(&Bs[ib][k][tx * 8]);
      {
        float4 v0 = bp[0], v1 = bp[1];
        b[0] = v0.x; b[1] = v0.y; b[2] = v0.z; b[3] = v0.w;
        b[4] = v1.x; b[5] = v1.y; b[6] = v1.z; b[7] = v1.w;
      }
      #pragma unroll
      for (int i = 0; i < TM; ++i)
        #pragma unroll
        for (int j = 0; j < 8; ++j) acc[i][j] = fmaf(a[i], b[j], acc[i][j]);
    }
  };

  if constexpr (MODE == 0) {
    for (int kt = 0; kt < K; kt += BK) {
      int k4 = (tid & (BK / 4 - 1)) * 4;
      constexpr int MSTEP = NT / (BK / 4);
      #pragma unroll
      for (int mm = tid / (BK / 4); mm < BM; mm += MSTEP) {
        const float4 v = *reinterpret_cast<const float4*>(
            in + (bm + mm) * (long)rmul1 + kt + k4);
        As[0][k4 + 0][mm] = v.x;
        As[0][k4 + 1][mm] = v.y;
        As[0][k4 + 2][mm] = v.z;
        As[0][k4 + 3][mm] = v.w;
      }
      int n4 = (tid % (BN / 4)) * 4;
      #pragma unroll
      for (int k = tid / (BN / 4); k < BK; k += (NT / (BN / 4))) {
        const float4 v = *reinterpret_cast<const float4*>(
            tab + (long)(kt + k) * N + bn + n4);
        Bs[0][k][n4 + 0] = v.x;
        Bs[0][k][n4 + 1] = v.y;
        Bs[0][k][n4 + 2] = v.z;
        Bs[0][k][n4 + 3] = v.w;
      }
      __syncthreads();
      compute(0);
      __syncthreads();
    }
  } else {
    // prologue: fill buffer 0
    if constexpr (MODE == 1) {
      stageA1(0, 0);
      stageB(0, 0);
    } else {
      loadA2(0);
      stageB(0, 0);
      writeA2(0);
    }
    __syncthreads();
    int ib = 0;
    for (int kt = 0; kt < K; kt += BK) {
      const int nt = kt + BK;
      if constexpr (MODE == 1) {
        if (nt < K) {
          stageA1(nt, ib ^ 1);
          stageB(nt, ib ^ 1);
        }
      } else {
        if (nt < K) {
          loadA2(nt);
          stageB(nt, ib ^ 1);
        }
      }
      compute(ib);
      if constexpr (MODE == 2) {
        if (nt < K) writeA2(ib ^ 1);
      }
      __syncthreads();
      ib ^= 1;
    }
  }

  #pragma unroll
  for (int i = 0; i < TM; ++i) {
    long row = bm + ty * TM + i;
    float4 v0 = make_float4(acc[i][0], acc[i][1], acc[i][2], acc[i][3]);
    float4 v1 = make_float4(acc[i][4], acc[i][5], acc[i][6], acc[i][7]);
    float* p = out + row * (long)N + bn + tx * 8;
    *reinterpret_cast<float4*>(p) = v0;
    *reinterpret_cast<float4*>(p + 4) = v1;
  }
}

// ---------------- stage C: per-mode complex channel mix ------------------------
__global__ __launch_bounds__(512) void modemix(
    const float* __restrict__ Bbuf, float* __restrict__ Cbuf,
    const float* __restrict__ w1r, const float* __restrict__ w1i,
    const float* __restrict__ w2r, const float* __restrict__ w2i,
    const float* __restrict__ w3r, const float* __restrict__ w3i,
    const float* __restrict__ w4r, const float* __restrict__ w4i) {
  __shared__ float2 Bin[8 * 32 * 16];  // [b][ii][kyl] complex, 32 KB
  const int tid = threadIdx.x;
  const int j = blockIdx.x;
  const int kyh = blockIdx.y;
  const int br = blockIdx.z;
  const float* wr;
  const float* wi;
  int kx;
  if (j < 32) {
    kx = j;
    wr = br ? w3r : w1r;
    wi = br ? w3i : w1i;
  } else {
    kx = j - 32;
    wr = br ? w4r : w2r;
    wi = br ? w4i : w2i;
  }
  const float* Bb = Bbuf + (long)br * 2097152;
  float* Cb = Cbuf + (long)br * 2097152;
  const int kyl = tid & 15;
  const int og = tid >> 4;  // 0..31
  const int o0 = og * 2;
  const int ky = kyh * 16 + kyl;
  float accr[8][2] = {}, acci[8][2] = {};

  for (int ic = 0; ic < 2; ++ic) {  // i chunks of 32
    __syncthreads();
    #pragma unroll
    for (int p = 0; p < 8; ++p) {
      int u = tid + p * 512;
      int ukyl = u & 15;
      int uii = (u >> 4) & 31;
      int ub = u >> 9;
      int i = ic * 32 + uii;
      int uky = kyh * 16 + ukyl;
      const float* src = Bb + ((long)((ub * 64 + i) * 32 + uky)) * 128 + 2 * j;
      Bin[(ub * 32 + uii) * 16 + ukyl] = *reinterpret_cast<const float2*>(src);
    }
    __syncthreads();
    for (int ii = 0; ii < 32; ++ii) {
      int i = ic * 32 + ii;
      long wbase = ((long)(i * 64 + o0) * 32 + kx) * 32 + ky;
      float wr0 = wr[wbase], wi0 = wi[wbase];
      float wr1 = wr[wbase + 1024], wi1 = wi[wbase + 1024];  // o0+1
      #pragma unroll
      for (int b = 0; b < 8; ++b) {
        float2 v = Bin[(b * 32 + ii) * 16 + kyl];
        accr[b][0] = fmaf(v.x, wr0, fmaf(-v.y, wi0, accr[b][0]));
        acci[b][0] = fmaf(v.x, wi0, fmaf(v.y, wr0, acci[b][0]));
        accr[b][1] = fmaf(v.x, wr1, fmaf(-v.y, wi1, accr[b][1]));
        acci[b][1] = fmaf(v.x, wi1, fmaf(v.y, wr1, acci[b][1]));
      }
    }
  }
  #pragma unroll
  for (int b = 0; b < 8; ++b) {
    #pragma unroll
    for (int q = 0; q < 2; ++q) {
      float2 v = make_float2(accr[b][q], acci[b][q]);
      float* dst = Cb + (long)b * 262144 + (long)j * 4096 + (o0 + q) * 64 + ky * 2;
      *reinterpret_cast<float2*>(dst) = v;
    }
  }
}

extern "C" void kernel_launch(void* const* d_in, const int* in_sizes, int n_in,
                              void* d_out, int out_size, void* d_ws,
                              size_t ws_size, hipStream_t stream) {
  const float* x = (const float*)d_in[0];
  const float* w1r = (const float*)d_in[1];
  const float* w1i = (const float*)d_in[2];
  const float* w2r = (const float*)d_in[3];
  const float* w2i = (const float*)d_in[4];
  const float* w3r = (const float*)d_in[5];
  const float* w3i = (const float*)d_in[6];
  const float* w4r = (const float*)d_in[7];
  const float* w4i = (const float*)d_in[8];
  float* ws = (float*)d_ws;

  float* TA = ws;                  // 16384
  float* TB = TA + 16384;          // 65536
  float* TD = TB + 65536;          // 65536
  float* TE = TD + 65536;          // 16384
  float* Abuf = TE + 16384;        // 16,777,216 floats (2 branches); aliased as Dbuf
  float* Bbuf = Abuf + 16777216;   // 4,194,304
  float* Cbuf = Bbuf + 4194304;    // 4,194,304
  float* Dbuf = Abuf;              // A dead after stage B
  float* out = (float*)d_out;

  // tables
  hipLaunchKernelGGL(tab_init, dim3(256), dim3(256), 0, stream, ws);

  // Stage A, branch X: rows = (b,c,h), contiguous k along W. KCONTIG, BK=32.
  hipLaunchKernelGGL((gemm_t<256, 64, 8, 0, 32>), dim3(512, 1, 1), dim3(256), 0,
                     stream, x, TA, Abuf, 256, 64, 1, 256, 0, 2, 1, 0L, 0L);
  // Stage A, branch Z: rows = (b,c,w'), k strides down H. MQUAD dbuf BK=16.
  hipLaunchKernelGGL((gemm_t<256, 64, 8, 1, 16>), dim3(512, 1, 1), dim3(256), 0,
                     stream, x, TA, Abuf + 8388608, 256, 64, 256, 65536, 1, 512,
                     256, 0L, 0L);
  // Stage B: rows = (b,c,ky); k = (h, re/im) in Abuf[(bc*256+h)*64 + 2ky+t].
  // MPAIR dbuf BK=16. TM=4 -> 512 blocks for occupancy.
  hipLaunchKernelGGL((gemm_t<128, 64, 4, 2, 16>), dim3(128, 2, 2), dim3(256), 0,
                     stream, Abuf, TB, Bbuf, 512, 128, 32, 16384, 2, 64, 1,
                     8388608L, 2097152L);
  // Stage C
  hipLaunchKernelGGL(modemix, dim3(64, 2, 2), dim3(512), 0, stream, Bbuf, Cbuf,
                     w1r, w1i, w2r, w2i, w3r, w3i, w4r, w4i);
  // Stage D: rows = (b,o,ky); Cbuf[b][j][o][ky][t]. MPAIR dbuf BK=16.
  hipLaunchKernelGGL((gemm_t<128, 128, 8, 2, 16>), dim3(128, 4, 2), dim3(256),
                     0, stream, Cbuf, TD, Dbuf, 128, 512, 2048, 262144, 2, 4096,
                     1, 2097152L, 8388608L);
  // Stage E: rows = (b,o,h); Dbuf[(bo*32+ky)*512 + 2h+s] -> d_out. MPAIR dbuf.
  hipLaunchKernelGGL((gemm_t<128, 128, 8, 2, 16>), dim3(1024, 2, 2), dim3(256),
                     0, stream, Dbuf, TE, out, 64, 256, 256, 16384, 2, 512, 1,
                     8388608L, 33554432L);
}

// Round 6
// 832.168 us; speedup vs baseline: 5.6695x; 5.6695x over previous
//
#include <hip/hip_runtime.h>

// SpectralConv2d (FNO) as a chain of truncated-DFT GEMMs. All fp32 vector math.
// B=8, CIN=COUT=64, H=W=256, M1=M2=32.
//
// Round 6: revert to the verified Round-3 kernel (842.7 us). The Round-4
// double-buffer restructure triggered a scratch-spill pathology (7.8 GB HBM
// traffic/dispatch, VALUBusy 3%). Baseline re-anchor; next change will be a
// register-neutral Bs-only prefetch.

#define PI_D 3.14159265358979323846

// ---------------- DFT table init (once per call; double precision) -------------
__global__ void tab_init(float* __restrict__ ws) {
  int t = blockIdx.x * blockDim.x + threadIdx.x;  // 0..65535
  float* TA = ws;                      // [256][64]
  float* TB = ws + 16384;              // [512][128]
  float* TD = ws + 16384 + 65536;      // [128][512]
  float* TE = ws + 16384 + 2 * 65536;  // [64][256]
  const double w0 = 2.0 * PI_D / 256.0;
  // T_A[n][2k+s]: s=0 -> cos(2pi n k/256), s=1 -> -sin
  if (t < 16384) {
    int n = t >> 6, c = t & 63, k = c >> 1, s = c & 1;
    int m = (n * k) & 255;
    double sv, cv; sincos(w0 * m, &sv, &cv);
    TA[t] = (float)(s ? -sv : cv);
  }
  // T_B[2h+ti][2j+s]: forward e^{-i theta}: [c, s; -s, c]
  {
    int r = t >> 7, c = t & 127;
    int h = r >> 1, ti = r & 1, j = c >> 1, s = c & 1;
    int kx = (j < 32) ? j : 192 + j;
    int m = (kx * h) & 255;
    double sv, cv; sincos(w0 * m, &sv, &cv);
    TB[t] = (float)((ti == s) ? cv : (ti ? sv : -sv));
  }
  // T_D[2j+ti][2h+s]: inverse e^{+i theta}
  {
    int r = t >> 9, c = t & 511;
    int j = r >> 1, ti = r & 1, h = c >> 1, s = c & 1;
    int kx = (j < 32) ? j : 192 + j;
    int m = (kx * h) & 255;
    double sv, cv; sincos(w0 * m, &sv, &cv);
    TD[t] = (float)((ti == s) ? cv : (ti ? -sv : sv));
  }
  // T_E[2k+s][w]: c_k/65536 * (cos | -sin); c_0=1 else 2.
  if (t < 16384) {
    int r = t >> 8, w = t & 255, k = r >> 1, s = r & 1;
    int m = (k * w) & 255;
    double sv, cv; sincos(w0 * m, &sv, &cv);
    double amp = (k == 0 ? 1.0 : 2.0) / 65536.0;
    TE[t] = (float)(s ? -amp * sv : amp * cv);
  }
}

// direct global->LDS async copy, 16B per lane. Dest must be wave-base+lane*16.
__device__ __forceinline__ void gl16(const float* g, float* l) {
  __builtin_amdgcn_global_load_lds(
      (const __attribute__((address_space(1))) void*)g,
      (__attribute__((address_space(3))) void*)l, 16, 0, 0);
}

// ---------------- generic tiled GEMM: out[M][N] = in[M][K] * tab[K][N] ---------
// Input addressing: row base = (row/rdiv)*rmul1 + (row%rdiv)*rmul2,
//                   k offset = (k>>1)*sH + (k&1)*sT.
// MODE 0 (KCONTIG): float4 loads along k (requires sH=2,sT=1). LDS padded.
// MODE 1 (MQUAD):   requires rmul2==1 -> float4 = 4 consecutive rows at fixed
//                   k; staged via global_load_lds (dest linear per wave).
// MODE 2 (MPAIR):   requires rmul2==2, sT==1 -> float4 = (m0,t0),(m0,t1),
//                   (m0+1,t0),(m0+1,t1); two ds_write_b64 per thread.
// Bs staging: MODE!=0 uses global_load_lds (rows contiguous, no pad).
// Per-thread tile = TM x 8. Threads = (BM/TM)*(BN/8).
// Wave-local 8x8 lane grid keeps LDS compute reads broadcast (<=2-way = free).
template <int BM, int BN, int TM, int MODE>
__global__ __launch_bounds__((BM / TM) * (BN / 8), MODE == 0 ? 4 : 5) void gemm_t(
    const float* __restrict__ in, const float* __restrict__ tab,
    float* __restrict__ out, int K, int N, int rdiv, int rmul1, int rmul2,
    int sH, int sT, long inStride, long outStride) {
  constexpr int NT = (BM / TM) * (BN / 8);
  constexpr int BK = 32;
  constexpr int CW = BN / 64;  // waves per column band
  constexpr int PAD = (MODE == 0) ? 4 : 0;
  __shared__ float As[BK][BM + PAD];
  __shared__ float Bs[BK][BN + PAD];
  const int tid = threadIdx.x;
  const int wave = tid >> 6, lane = tid & 63;
  const int tx = (wave % CW) * 8 + (lane & 7);
  const int ty = (wave / CW) * 8 + (lane >> 3);
  const long bm = (long)blockIdx.x * BM;
  const int bn = blockIdx.y * BN;
  in += (long)blockIdx.z * inStride;
  out += (long)blockIdx.z * outStride;
  float acc[TM][8] = {};

  long abase = 0;
  int am = 0;
  if constexpr (MODE == 0) {
    am = tid >> 3;  // starting m, step NT/8
  } else if constexpr (MODE == 1) {
    am = 4 * (tid % (BM / 4));
    int row = (int)bm + am;
    abase = (long)(row / rdiv) * rmul1 + (long)(row % rdiv) * rmul2;
  } else {
    am = 2 * (tid % (BM / 2));
    int row = (int)bm + am;
    abase = (long)(row / rdiv) * rmul1 + (long)(row % rdiv) * rmul2;
  }

  for (int kt = 0; kt < K; kt += BK) {
    // ---- A tile ----
    if constexpr (MODE == 0) {
      int k4 = (tid & 7) * 4;
      #pragma unroll
      for (int mm = am; mm < BM; mm += NT / 8) {
        const float4 v = *reinterpret_cast<const float4*>(
            in + (bm + mm) * (long)rmul1 + kt + k4);
        As[k4 + 0][mm] = v.x;
        As[k4 + 1][mm] = v.y;
        As[k4 + 2][mm] = v.z;
        As[k4 + 3][mm] = v.w;
      }
    } else if constexpr (MODE == 1) {
      constexpr int KSTEP = NT / (BM / 4);
      #pragma unroll
      for (int k = tid / (BM / 4); k < BK; k += KSTEP) {
        int kg = kt + k;
        gl16(in + abase + (long)(kg >> 1) * sH + (long)(kg & 1) * sT,
             &As[k][am]);
      }
    } else {
      constexpr int KH = NT / (BM / 2);  // khi rows per pass
      #pragma unroll
      for (int i = 0; i < (BK / 2) / KH; ++i) {
        int khi = tid / (BM / 2) + i * KH;
        const float4 v = *reinterpret_cast<const float4*>(
            in + abase + (long)(kt / 2 + khi) * sH);
        *reinterpret_cast<float2*>(&As[2 * khi][am]) = make_float2(v.x, v.z);
        *reinterpret_cast<float2*>(&As[2 * khi + 1][am]) = make_float2(v.y, v.w);
      }
    }
    // ---- B tile ----
    if constexpr (MODE == 0) {
      int n4 = (tid % (BN / 4)) * 4;
      #pragma unroll
      for (int k = tid / (BN / 4); k < BK; k += (NT / (BN / 4))) {
        const float4 v = *reinterpret_cast<const float4*>(
            tab + (long)(kt + k) * N + bn + n4);
        Bs[k][n4 + 0] = v.x;
        Bs[k][n4 + 1] = v.y;
        Bs[k][n4 + 2] = v.z;
        Bs[k][n4 + 3] = v.w;
      }
    } else {
      int n4 = (tid % (BN / 4)) * 4;
      #pragma unroll
      for (int k = tid / (BN / 4); k < BK; k += (NT / (BN / 4))) {
        gl16(tab + (long)(kt + k) * N + bn + n4, &Bs[k][n4]);
      }
    }
    __syncthreads();
    #pragma unroll
    for (int k = 0; k < BK; ++k) {
      float a[TM], b[8];
      const float4* ap = reinterpret_cast<const float4*>(&As[k][ty * TM]);
      #pragma unroll
      for (int i = 0; i < TM / 4; ++i) {
        float4 v = ap[i];
        a[i * 4 + 0] = v.x; a[i * 4 + 1] = v.y;
        a[i * 4 + 2] = v.z; a[i * 4 + 3] = v.w;
      }
      const float4* bp = reinterpret_cast<const float4*>(&Bs[k][tx * 8]);
      {
        float4 v0 = bp[0], v1 = bp[1];
        b[0] = v0.x; b[1] = v0.y; b[2] = v0.z; b[3] = v0.w;
        b[4] = v1.x; b[5] = v1.y; b[6] = v1.z; b[7] = v1.w;
      }
      #pragma unroll
      for (int i = 0; i < TM; ++i)
        #pragma unroll
        for (int j = 0; j < 8; ++j) acc[i][j] = fmaf(a[i], b[j], acc[i][j]);
    }
    __syncthreads();
  }

  #pragma unroll
  for (int i = 0; i < TM; ++i) {
    long row = bm + ty * TM + i;
    float4 v0 = make_float4(acc[i][0], acc[i][1], acc[i][2], acc[i][3]);
    float4 v1 = make_float4(acc[i][4], acc[i][5], acc[i][6], acc[i][7]);
    float* p = out + row * (long)N + bn + tx * 8;
    *reinterpret_cast<float4*>(p) = v0;
    *reinterpret_cast<float4*>(p + 4) = v1;
  }
}

// ---------------- stage C: per-mode complex channel mix ------------------------
__global__ __launch_bounds__(512) void modemix(
    const float* __restrict__ Bbuf, float* __restrict__ Cbuf,
    const float* __restrict__ w1r, const float* __restrict__ w1i,
    const float* __restrict__ w2r, const float* __restrict__ w2i,
    const float* __restrict__ w3r, const float* __restrict__ w3i,
    const float* __restrict__ w4r, const float* __restrict__ w4i) {
  __shared__ float2 Bin[8 * 32 * 16];  // [b][ii][kyl] complex, 32 KB
  const int tid = threadIdx.x;
  const int j = blockIdx.x;
  const int kyh = blockIdx.y;
  const int br = blockIdx.z;
  const float* wr;
  const float* wi;
  int kx;
  if (j < 32) {
    kx = j;
    wr = br ? w3r : w1r;
    wi = br ? w3i : w1i;
  } else {
    kx = j - 32;
    wr = br ? w4r : w2r;
    wi = br ? w4i : w2i;
  }
  const float* Bb = Bbuf + (long)br * 2097152;
  float* Cb = Cbuf + (long)br * 2097152;
  const int kyl = tid & 15;
  const int og = tid >> 4;  // 0..31
  const int o0 = og * 2;
  const int ky = kyh * 16 + kyl;
  float accr[8][2] = {}, acci[8][2] = {};

  for (int ic = 0; ic < 2; ++ic) {  // i chunks of 32
    __syncthreads();
    #pragma unroll
    for (int p = 0; p < 8; ++p) {
      int u = tid + p * 512;
      int ukyl = u & 15;
      int uii = (u >> 4) & 31;
      int ub = u >> 9;
      int i = ic * 32 + uii;
      int uky = kyh * 16 + ukyl;
      const float* src = Bb + ((long)((ub * 64 + i) * 32 + uky)) * 128 + 2 * j;
      Bin[(ub * 32 + uii) * 16 + ukyl] = *reinterpret_cast<const float2*>(src);
    }
    __syncthreads();
    for (int ii = 0; ii < 32; ++ii) {
      int i = ic * 32 + ii;
      long wbase = ((long)(i * 64 + o0) * 32 + kx) * 32 + ky;
      float wr0 = wr[wbase], wi0 = wi[wbase];
      float wr1 = wr[wbase + 1024], wi1 = wi[wbase + 1024];  // o0+1
      #pragma unroll
      for (int b = 0; b < 8; ++b) {
        float2 v = Bin[(b * 32 + ii) * 16 + kyl];
        accr[b][0] = fmaf(v.x, wr0, fmaf(-v.y, wi0, accr[b][0]));
        acci[b][0] = fmaf(v.x, wi0, fmaf(v.y, wr0, acci[b][0]));
        accr[b][1] = fmaf(v.x, wr1, fmaf(-v.y, wi1, accr[b][1]));
        acci[b][1] = fmaf(v.x, wi1, fmaf(v.y, wr1, acci[b][1]));
      }
    }
  }
  #pragma unroll
  for (int b = 0; b < 8; ++b) {
    #pragma unroll
    for (int q = 0; q < 2; ++q) {
      float2 v = make_float2(accr[b][q], acci[b][q]);
      float* dst = Cb + (long)b * 262144 + (long)j * 4096 + (o0 + q) * 64 + ky * 2;
      *reinterpret_cast<float2*>(dst) = v;
    }
  }
}

extern "C" void kernel_launch(void* const* d_in, const int* in_sizes, int n_in,
                              void* d_out, int out_size, void* d_ws,
                              size_t ws_size, hipStream_t stream) {
  const float* x = (const float*)d_in[0];
  const float* w1r = (const float*)d_in[1];
  const float* w1i = (const float*)d_in[2];
  const float* w2r = (const float*)d_in[3];
  const float* w2i = (const float*)d_in[4];
  const float* w3r = (const float*)d_in[5];
  const float* w3i = (const float*)d_in[6];
  const float* w4r = (const float*)d_in[7];
  const float* w4i = (const float*)d_in[8];
  float* ws = (float*)d_ws;

  float* TA = ws;                  // 16384
  float* TB = TA + 16384;          // 65536
  float* TD = TB + 65536;          // 65536
  float* TE = TD + 65536;          // 16384
  float* Abuf = TE + 16384;        // 16,777,216 floats (2 branches); aliased as Dbuf
  float* Bbuf = Abuf + 16777216;   // 4,194,304
  float* Cbuf = Bbuf + 4194304;    // 4,194,304
  float* Dbuf = Abuf;              // A dead after stage B
  float* out = (float*)d_out;

  // tables
  hipLaunchKernelGGL(tab_init, dim3(256), dim3(256), 0, stream, ws);

  // Stage A, branch X: rows = (b,c,h), contiguous k along W. KCONTIG.
  hipLaunchKernelGGL((gemm_t<256, 64, 8, 0>), dim3(512, 1, 1), dim3(256), 0,
                     stream, x, TA, Abuf, 256, 64, 1, 256, 0, 2, 1, 0L, 0L);
  // Stage A, branch Z: rows = (b,c,w'), k strides down H. MQUAD loader.
  hipLaunchKernelGGL((gemm_t<256, 64, 8, 1>), dim3(512, 1, 1), dim3(256), 0,
                     stream, x, TA, Abuf + 8388608, 256, 64, 256, 65536, 1, 512,
                     256, 0L, 0L);
  // Stage B: rows = (b,c,ky); k = (h, re/im) in Abuf[(bc*256+h)*64 + 2ky+t].
  // MPAIR. TM=4 -> 512 blocks for occupancy.
  hipLaunchKernelGGL((gemm_t<128, 64, 4, 2>), dim3(128, 2, 2), dim3(256), 0,
                     stream, Abuf, TB, Bbuf, 512, 128, 32, 16384, 2, 64, 1,
                     8388608L, 2097152L);
  // Stage C
  hipLaunchKernelGGL(modemix, dim3(64, 2, 2), dim3(512), 0, stream, Bbuf, Cbuf,
                     w1r, w1i, w2r, w2i, w3r, w3i, w4r, w4i);
  // Stage D: rows = (b,o,ky); Cbuf[b][j][o][ky][t]. MPAIR.
  hipLaunchKernelGGL((gemm_t<128, 128, 8, 2>), dim3(128, 4, 2), dim3(256),
                     0, stream, Cbuf, TD, Dbuf, 128, 512, 2048, 262144, 2, 4096,
                     1, 2097152L, 8388608L);
  // Stage E: rows = (b,o,h); Dbuf[(bo*32+ky)*512 + 2h+s] -> d_out. MPAIR.
  hipLaunchKernelGGL((gemm_t<128, 128, 8, 2>), dim3(1024, 2, 2), dim3(256),
                     0, stream, Dbuf, TE, out, 64, 256, 256, 16384, 2, 512, 1,
                     8388608L, 33554432L);
}